// Round 3
// baseline (2508.681 us; speedup 1.0000x reference)
//
#include <hip/hip_runtime.h>

typedef __bf16 v8bf __attribute__((ext_vector_type(8)));
typedef float v4f __attribute__((ext_vector_type(4)));
typedef unsigned short u16;
typedef unsigned int u32;

#define DEVI __device__ __forceinline__

constexpr int LX = 168, FF = 64;
constexpr int LY = 72, FT = 22, FOUTC = 10;
constexpr int HID = 256;
constexpr int USTR = 296;   // u16/row: [0,32) dec input, [32,288) h, pad; 592B = 37*16
constexpr int A1STR = 264;  // u16/row: 528B = 33*16

// bf16 weight cache layout in d_ws (u16 element offsets; all 16B-aligned)
constexpr int W_EWIH = 0;                      // 768*64
constexpr int W_EWHH = 49152;                  // 768*256
constexpr int W_DWIH = 245760;                 // 768*32
constexpr int W_DWHH = 270336;                 // 768*256
constexpr int W_THW0 = 466944;                 // 128*256
constexpr int W_THW1 = 499712;                 // 2*128
constexpr int W_CLW0 = 499968;                 // 128*256
constexpr int W_CLW1 = 532736;                 // 8*128
constexpr int W_TOTAL = 533760;                // ~1.04 MB as u16

DEVI u16 f2bf(float f) {
  u32 x; __builtin_memcpy(&x, &f, 4);
  return (u16)((x + 0x7FFFu + ((x >> 16) & 1u)) >> 16);  // RNE
}
DEVI float sigm(float x) { return 1.f / (1.f + __expf(-x)); }
DEVI float tanh_(float x) {
  float e = __expf(-2.f * fabsf(x));
  return copysignf((1.f - e) / (1.f + e), x);
}
DEVI float smelu_(float x) {
  if (x >= 1.1f) return x;
  if (x <= -1.1f) return 0.f;
  float u = x + 1.1f;
  return u * u * (1.f / 4.4f);
}
DEVI v8bf ld8(const u16* p) { return *reinterpret_cast<const v8bf*>(p); }
DEVI v8bf cvt8(const float* p) {  // 8 f32 -> bf16x8 (compiler emits 2x dwordx4)
  v8bf r;
#pragma unroll
  for (int j = 0; j < 8; ++j) r[j] = (__bf16)p[j];
  return r;
}
DEVI v4f mfma16(v8bf a, v8bf b, v4f c) {
  return __builtin_amdgcn_mfma_f32_16x16x32_bf16(a, b, c, 0, 0, 0);
}

// ---- prologue: convert all weight matrices f32 -> bf16 into d_ws ----
__global__ void cvt_weights(const float* __restrict__ eWih, const float* __restrict__ eWhh,
                            const float* __restrict__ dWih, const float* __restrict__ dWhh,
                            const float* __restrict__ thW0, const float* __restrict__ thW1,
                            const float* __restrict__ clW0, const float* __restrict__ clW1,
                            u16* __restrict__ ws) {
  const int i = blockIdx.x * 256 + threadIdx.x;
  if (i >= W_TOTAL) return;
  const float* src; int off;
  if      (i < W_EWHH) { src = eWih; off = W_EWIH; }
  else if (i < W_DWIH) { src = eWhh; off = W_EWHH; }
  else if (i < W_DWHH) { src = dWih; off = W_DWIH; }
  else if (i < W_THW0) { src = dWhh; off = W_DWHH; }
  else if (i < W_THW1) { src = thW0; off = W_THW0; }
  else if (i < W_CLW0) { src = thW1; off = W_THW1; }
  else if (i < W_CLW1) { src = clW0; off = W_CLW0; }
  else                 { src = clW1; off = W_CLW1; }
  ws[i] = f2bf(src[i - off]);
}

// 6 gate tiles (r:i=0,1  z:i=2,3  n:i=4,5). For aligned tiles, r/z/i_n/h_n/h
// for one (batch,hid) element all live in the SAME lane+slot, so the whole
// GRU update is lane-local; h master copy stays in fp32 regs.
template <int KIN>
DEVI void gru_gates(const v8bf* a, const u16* __restrict__ Wih,
                    const u16* __restrict__ Whh,
                    const float (&bi)[6], const float (&bh)[6],
                    float (&hreg)[2][4], int wave, int col16, int quad) {
  constexpr int NKI = KIN / 32;
  float sr[2][4], sz[2][4], pi[2][4], ph[2][4];
#pragma unroll
  for (int i = 0; i < 6; ++i) {
    const int m = (wave + 8 * i) * 16 + col16;  // gate row of W (B's n index)
    const u16* pih = Wih + (size_t)m * KIN + quad * 8;
    const u16* phh = Whh + (size_t)m * HID + quad * 8;
    v4f ai = {0.f, 0.f, 0.f, 0.f};
    v4f ah = {0.f, 0.f, 0.f, 0.f};
#pragma unroll
    for (int kt = 0; kt < NKI; ++kt)
      ai = mfma16(a[kt], ld8(pih + kt * 32), ai);
#pragma unroll
    for (int kt = 0; kt < 8; ++kt)
      ah = mfma16(a[NKI + kt], ld8(phh + kt * 32), ah);
#pragma unroll
    for (int r = 0; r < 4; ++r) {
      const float vi = ai[r] + bi[i];
      const float vh = ah[r] + bh[i];
      if (i < 2)      sr[i][r] = vi + vh;
      else if (i < 4) sz[i - 2][r] = vi + vh;
      else { pi[i - 4][r] = vi; ph[i - 4][r] = vh; }
    }
  }
#pragma unroll
  for (int j = 0; j < 2; ++j)
#pragma unroll
    for (int r = 0; r < 4; ++r) {
      const float rg = sigm(sr[j][r]);
      const float zg = sigm(sz[j][r]);
      const float ng = tanh_(pi[j][r] + rg * ph[j][r]);
      hreg[j][r] = (1.f - zg) * ng + zg * hreg[j][r];
    }
}

__global__ __launch_bounds__(512, 1) void encdec_kernel(
    const float* __restrict__ xf, const float* __restrict__ yt, const float* __restrict__ pp,
    const float* __restrict__ ebih, const float* __restrict__ ebhh,
    const float* __restrict__ dbih, const float* __restrict__ dbhh,
    const float* __restrict__ thb0, const float* __restrict__ thb1,
    const float* __restrict__ clb0, const float* __restrict__ clb1,
    const u16* __restrict__ ws, float* __restrict__ outp) {
  __shared__ __align__(16) u16 Ubuf[16 * USTR];
  __shared__ __align__(16) u16 a1buf[16 * A1STR];

  const u16* eWih = ws + W_EWIH;
  const u16* eWhh = ws + W_EWHH;
  const u16* dWih = ws + W_DWIH;
  const u16* dWhh = ws + W_DWHH;
  const u16* thW0 = ws + W_THW0;
  const u16* thW1 = ws + W_THW1;
  const u16* clW0 = ws + W_CLW0;
  const u16* clW1 = ws + W_CLW1;

  const int tid = threadIdx.x;
  const int wave = tid >> 6;
  const int lane = tid & 63;
  const int col16 = lane & 15;
  const int quad = lane >> 4;
  const int n0 = blockIdx.x * 16;

  for (int idx = tid; idx < 16 * USTR; idx += 512) Ubuf[idx] = 0;

  float hreg[2][4];
#pragma unroll
  for (int j = 0; j < 2; ++j)
#pragma unroll
    for (int r = 0; r < 4; ++r) hreg[j][r] = 0.f;

  float bi[6], bh[6];
#pragma unroll
  for (int i = 0; i < 6; ++i) {
    const int m = (wave + 8 * i) * 16 + col16;
    bi[i] = ebih[m];
    bh[i] = ebhh[m];
  }
  __syncthreads();  // Ubuf zero-init visible

  const u16* hrow = Ubuf + col16 * USTR + 32 + quad * 8;  // lane's h A-frag base

  // ---------------- encoder: 168 steps ----------------
#pragma unroll 1
  for (int t = 0; t < LX; ++t) {
    v8bf a[10];
    // x fragments straight from global (f32 -> bf16): A[m=batch=col16][k]
    const float* xrow = xf + ((size_t)(n0 + col16) * LX + t) * FF + quad * 8;
    a[0] = cvt8(xrow);
    a[1] = cvt8(xrow + 32);
#pragma unroll
    for (int kt = 0; kt < 8; ++kt) a[2 + kt] = ld8(hrow + kt * 32);  // h_{t-1}
    gru_gates<64>(a, eWih, eWhh, bi, bh, hreg, wave, col16, quad);
    __syncthreads();  // all waves' h A-frag reads complete
#pragma unroll
    for (int j = 0; j < 2; ++j) {
      const int cidx = (wave + 8 * j) * 16 + col16;
#pragma unroll
      for (int r = 0; r < 4; ++r)
        Ubuf[(quad * 4 + r) * USTR + 32 + cidx] = f2bf(hreg[j][r]);
    }
    __syncthreads();  // h_t visible for next step
  }

  // ---------------- decoder setup ----------------
#pragma unroll
  for (int i = 0; i < 6; ++i) {
    const int m = (wave + 8 * i) * 16 + col16;
    bi[i] = dbih[m];
    bh[i] = dbhh[m];
  }
  float hb0[2];
#pragma unroll
  for (int i = 0; i < 2; ++i) {
    const int ct = wave + 8 * i;
    const int ml = (ct & 7) * 16 + col16;
    hb0[i] = (ct < 8) ? thb0[ml] : clb0[ml];
  }
  const bool w1th = (col16 < 2);
  const bool w1cl = (col16 >= 2 && col16 < FOUTC);
  const float b1v = w1th ? thb1[col16] : (w1cl ? clb1[col16 - 2] : 0.f);

  // ---------------- decoder: 72 steps ----------------
#pragma unroll 1
  for (int t = 0; t < LY; ++t) {
    {  // stage u_t = [y_t | p] (16 x 32, f32->bf16) into U[:, 0:32)
      const int src_t = (t == 0) ? 0 : t - 1;
      const int rr = tid >> 5, cc = tid & 31;
      float v;
      if (cc < FT)
        v = yt[((size_t)(n0 + rr) * (LY + 1) + src_t) * FT + cc];
      else
        v = pp[((size_t)(n0 + rr) * (LY + 1) + src_t) * FOUTC + (cc - FT)];
      Ubuf[rr * USTR + cc] = f2bf(v);
    }
    __syncthreads();  // staging visible (h_{t-1} visible from prev barriers)

    v8bf a[9];
    a[0] = ld8(Ubuf + col16 * USTR + quad * 8);
#pragma unroll
    for (int kt = 0; kt < 8; ++kt) a[1 + kt] = ld8(hrow + kt * 32);
    gru_gates<32>(a, dWih, dWhh, bi, bh, hreg, wave, col16, quad);
    __syncthreads();  // all A-frag reads complete
#pragma unroll
    for (int j = 0; j < 2; ++j) {
      const int cidx = (wave + 8 * j) * 16 + col16;
#pragma unroll
      for (int r = 0; r < 4; ++r)
        Ubuf[(quad * 4 + r) * USTR + 32 + cidx] = f2bf(hreg[j][r]);
    }
    __syncthreads();  // h_t (= h2) visible

    // head GEMM1: a1 = smelu(h2 @ W0^T + b0); tiles 0-7 temphr, 8-15 class
    {
      v8bf ah2[8];
#pragma unroll
      for (int kt = 0; kt < 8; ++kt) ah2[kt] = ld8(hrow + kt * 32);
#pragma unroll
      for (int i = 0; i < 2; ++i) {
        const int ct = wave + 8 * i;
        const u16* W0 = (ct < 8) ? thW0 : clW0;
        const int ml = (ct & 7) * 16 + col16;
        const u16* pw = W0 + (size_t)ml * HID + quad * 8;
        v4f acc = {0.f, 0.f, 0.f, 0.f};
#pragma unroll
        for (int kt = 0; kt < 8; ++kt)
          acc = mfma16(ah2[kt], ld8(pw + kt * 32), acc);
#pragma unroll
        for (int r = 0; r < 4; ++r)
          a1buf[(quad * 4 + r) * A1STR + ct * 16 + col16] =
              f2bf(smelu_(acc[r] + hb0[i]));
      }
    }
    __syncthreads();  // a1 visible

    // head GEMM2 (wave 0): one K=256 pass, block-diag B = thW1 (+) clW1
    if (wave == 0) {
      const u16* arow = a1buf + col16 * A1STR + quad * 8;
      v4f acc = {0.f, 0.f, 0.f, 0.f};
#pragma unroll
      for (int kt = 0; kt < 8; ++kt) {
        v8bf b;
#pragma unroll
        for (int j = 0; j < 8; ++j) b[j] = (__bf16)0.0f;
        if (kt < 4) {
          if (w1th) b = ld8(thW1 + col16 * 128 + kt * 32 + quad * 8);
        } else {
          if (w1cl) b = ld8(clW1 + (col16 - 2) * 128 + (kt - 4) * 32 + quad * 8);
        }
        acc = mfma16(ld8(arow + kt * 32), b, acc);
      }
      if (col16 < FOUTC) {
#pragma unroll
        for (int r = 0; r < 4; ++r)
          outp[((size_t)(n0 + quad * 4 + r) * LY + t) * FOUTC + col16] =
              acc[r] + b1v;
      }
    }
    // next staging writes U[0:32) only; all a1buf reads completed before the
    // 3 barriers that precede the next a1buf write.
  }
}

extern "C" void kernel_launch(void* const* d_in, const int* in_sizes, int n_in,
                              void* d_out, int out_size, void* d_ws, size_t ws_size,
                              hipStream_t stream) {
  (void)in_sizes; (void)n_in; (void)ws_size; (void)out_size;
  const float* xf   = (const float*)d_in[0];
  // d_in[1] = x : unused by forward
  const float* yt   = (const float*)d_in[2];
  const float* pp   = (const float*)d_in[3];
  const float* eWih = (const float*)d_in[4];
  const float* eWhh = (const float*)d_in[5];
  const float* ebih = (const float*)d_in[6];
  const float* ebhh = (const float*)d_in[7];
  const float* dWih = (const float*)d_in[8];
  const float* dWhh = (const float*)d_in[9];
  const float* dbih = (const float*)d_in[10];
  const float* dbhh = (const float*)d_in[11];
  const float* thW0 = (const float*)d_in[12];
  const float* thb0 = (const float*)d_in[13];
  const float* thW1 = (const float*)d_in[14];
  const float* thb1 = (const float*)d_in[15];
  const float* clW0 = (const float*)d_in[16];
  const float* clb0 = (const float*)d_in[17];
  const float* clW1 = (const float*)d_in[18];
  const float* clb1 = (const float*)d_in[19];
  float* outp = (float*)d_out;
  u16* ws = (u16*)d_ws;  // needs W_TOTAL*2 ~= 1.04 MB of scratch

  cvt_weights<<<dim3((W_TOTAL + 255) / 256), dim3(256), 0, stream>>>(
      eWih, eWhh, dWih, dWhh, thW0, thW1, clW0, clW1, ws);
  encdec_kernel<<<dim3(128), dim3(512), 0, stream>>>(
      xf, yt, pp, ebih, ebhh, dbih, dbhh, thb0, thb1, clb0, clb1, ws, outp);
}